// Round 1
// baseline (460.504 us; speedup 1.0000x reference)
//
#include <hip/hip_runtime.h>

#define DEV __device__ __forceinline__

#if __has_builtin(__builtin_amdgcn_sdot4)
DEV int dot4i(unsigned int a, unsigned int b, int c) {
    return __builtin_amdgcn_sdot4((int)a, (int)b, c, false);
}
#else
DEV int dot4i(unsigned int a, unsigned int b, int c) {
#pragma unroll
    for (int i = 0; i < 4; ++i) {
        c += (int)((signed char)((a >> (8 * i)) & 0xff)) *
             (int)((signed char)((b >> (8 * i)) & 0xff));
    }
    return c;
}
#endif

DEV unsigned char quant2(float y) {
    y = fminf(fmaxf(y, 0.f), 1.f);
    return (unsigned char)(int)rintf(y * 3.f);
}

// ---------------------------------------------------------------------------
// Sign precompute: w2/w3 [co][ci][3][3] -> s8 [co][t][ci] (t=ky*3+kx), fw1 -> s8
// ---------------------------------------------------------------------------
__global__ __launch_bounds__(256) void k_signs(
    const float* __restrict__ w2, const float* __restrict__ w3,
    const float* __restrict__ fw1,
    char* __restrict__ w2s, char* __restrict__ w3s, char* __restrict__ fw1s) {
    int i = blockIdx.x * 256 + threadIdx.x;
    if (i < 36864) {
        int co = i / 576, r = i - co * 576;
        int ci = r / 9, k = r - ci * 9;
        w2s[co * 576 + k * 64 + ci] = (w2[i] >= 0.f) ? 1 : -1;
        w3s[co * 576 + k * 64 + ci] = (w3[i] >= 0.f) ? 1 : -1;
    }
    if (i < 819200) fw1s[i] = (fw1[i] >= 0.f) ? 1 : -1;
}

// ---------------------------------------------------------------------------
// conv1 (1->64, 3x3, pad1) + bias + maxpool2 + clip + quant -> a1 [b][14][14][64] u8
// one block per image; thread = (cg 0..15 -> 4 channels, pg 0..15 -> pixels)
// ---------------------------------------------------------------------------
__global__ __launch_bounds__(256) void k_conv1(
    const float* __restrict__ x, const float* __restrict__ w1f,
    const float* __restrict__ b1, unsigned char* __restrict__ a1) {
    __shared__ float sx[784];
    __shared__ float sw[576];
    __shared__ float sb[64];
    int b = blockIdx.x;
    int tid = threadIdx.x;
    for (int i = tid; i < 784; i += 256) sx[i] = x[(size_t)b * 784 + i];
    for (int i = tid; i < 576; i += 256) sw[i] = (w1f[i] >= 0.f) ? 1.f : -1.f;
    if (tid < 64) sb[tid] = b1[tid];
    __syncthreads();

    int cg = tid & 15;   // channel group: c = cg*4 + cc
    int pg = tid >> 4;   // pixel group

    float wv[4][9];
#pragma unroll
    for (int cc = 0; cc < 4; ++cc)
#pragma unroll
        for (int k = 0; k < 9; ++k) wv[cc][k] = sw[(cg * 4 + cc) * 9 + k];
    float bias[4];
#pragma unroll
    for (int cc = 0; cc < 4; ++cc) bias[cc] = sb[cg * 4 + cc];

    for (int p = pg; p < 196; p += 16) {
        int py = p / 14, px = p - py * 14;
        float xp[4][4];
#pragma unroll
        for (int r = 0; r < 4; ++r) {
            int iy = 2 * py - 1 + r;
#pragma unroll
            for (int s2 = 0; s2 < 4; ++s2) {
                int ix = 2 * px - 1 + s2;
                xp[r][s2] = ((unsigned)iy < 28u && (unsigned)ix < 28u)
                                ? sx[iy * 28 + ix] : 0.f;
            }
        }
        uchar4 ov;
        unsigned char oc[4];
#pragma unroll
        for (int cc = 0; cc < 4; ++cc) {
            float m = -1e30f;
#pragma unroll
            for (int dy = 0; dy < 2; ++dy)
#pragma unroll
                for (int dx = 0; dx < 2; ++dx) {
                    float s = 0.f;
#pragma unroll
                    for (int ky = 0; ky < 3; ++ky)
#pragma unroll
                        for (int kx = 0; kx < 3; ++kx)
                            s += wv[cc][ky * 3 + kx] * xp[dy + ky][dx + kx];
                    m = fmaxf(m, s);
                }
            oc[cc] = quant2(m + bias[cc]);
        }
        ov.x = oc[0]; ov.y = oc[1]; ov.z = oc[2]; ov.w = oc[3];
        *(uchar4*)(a1 + (size_t)b * 12544 + p * 64 + cg * 4) = ov;
    }
}

// ---------------------------------------------------------------------------
// conv2 (64->64, 3x3, pad1) + bn1 + maxpool2 + clip + quant -> a2 [b][7][7][64]
// one block per image. thread = (c0 0..31 -> channels c0, c0+32 ; pg 0..7)
// int8 dot products over channels-last LDS tiles.
// ---------------------------------------------------------------------------
__global__ __launch_bounds__(256) void k_conv2(
    const unsigned char* __restrict__ a1, const char* __restrict__ w2s,
    const float* __restrict__ g1, const float* __restrict__ be1,
    const float* __restrict__ m1, const float* __restrict__ v1,
    unsigned char* __restrict__ a2) {
    __shared__ unsigned char sa[12544];        // [14][14][64]
    __shared__ char sw[64 * 592];              // [c][t*64+ci], stride 592 (bank spread)
    __shared__ float sm[64], si[64], sbe[64];
    int b = blockIdx.x;
    int tid = threadIdx.x;
    {
        const uint4* src = (const uint4*)(a1 + (size_t)b * 12544);
        uint4* dst = (uint4*)sa;
        for (int i = tid; i < 784; i += 256) dst[i] = src[i];
        for (int u = tid; u < 2304; u += 256) {
            int c = u / 36, seg = u - c * 36;
            *(uint4*)(sw + c * 592 + seg * 16) =
                *(const uint4*)(w2s + c * 576 + seg * 16);
        }
        if (tid < 64) {
            sm[tid] = m1[tid];
            si[tid] = g1[tid] / sqrtf(v1[tid] + 1e-4f);
            sbe[tid] = be1[tid];
        }
    }
    __syncthreads();

    int c0 = tid & 31;
    int pg = tid >> 5;
    int oy0[7], ox0[7];
#pragma unroll
    for (int j = 0; j < 7; ++j) {
        int p = pg + 8 * j;
        int py = p / 7;
        oy0[j] = (p < 49) ? py * 2 : -1000;
        ox0[j] = (p - py * 7) * 2;
    }
    int acc[7][2][2][2];
#pragma unroll
    for (int j = 0; j < 7; ++j)
#pragma unroll
        for (int dy = 0; dy < 2; ++dy)
#pragma unroll
            for (int dx = 0; dx < 2; ++dx) {
                acc[j][dy][dx][0] = 0;
                acc[j][dy][dx][1] = 0;
            }

    for (int t = 0; t < 9; ++t) {
        int ky = t / 3, kx = t - ky * 3;
        uint4 wq0[4], wq1[4];
        {
            const uint4* wp0 = (const uint4*)(sw + c0 * 592 + t * 64);
            const uint4* wp1 = (const uint4*)(sw + (c0 + 32) * 592 + t * 64);
#pragma unroll
            for (int d = 0; d < 4; ++d) { wq0[d] = wp0[d]; wq1[d] = wp1[d]; }
        }
#pragma unroll
        for (int j = 0; j < 7; ++j) {
#pragma unroll
            for (int dy = 0; dy < 2; ++dy) {
                int iy = oy0[j] + dy + ky - 1;
                if ((unsigned)iy >= 14u) continue;
#pragma unroll
                for (int dx = 0; dx < 2; ++dx) {
                    int ix = ox0[j] + dx + kx - 1;
                    if ((unsigned)ix >= 14u) continue;
                    const uint4* ap = (const uint4*)(sa + (iy * 14 + ix) * 64);
                    int s0 = acc[j][dy][dx][0], s1 = acc[j][dy][dx][1];
#pragma unroll
                    for (int d = 0; d < 4; ++d) {
                        uint4 av = ap[d];
                        s0 = dot4i(av.x, wq0[d].x, s0);
                        s0 = dot4i(av.y, wq0[d].y, s0);
                        s0 = dot4i(av.z, wq0[d].z, s0);
                        s0 = dot4i(av.w, wq0[d].w, s0);
                        s1 = dot4i(av.x, wq1[d].x, s1);
                        s1 = dot4i(av.y, wq1[d].y, s1);
                        s1 = dot4i(av.z, wq1[d].z, s1);
                        s1 = dot4i(av.w, wq1[d].w, s1);
                    }
                    acc[j][dy][dx][0] = s0;
                    acc[j][dy][dx][1] = s1;
                }
            }
        }
    }

    const float inv3 = 1.f / 3.f;
#pragma unroll
    for (int j = 0; j < 7; ++j) {
        int p = pg + 8 * j;
        if (p >= 49) continue;
#pragma unroll
        for (int cc = 0; cc < 2; ++cc) {
            int c = c0 + 32 * cc;
            float mm = -1e30f;
#pragma unroll
            for (int dy = 0; dy < 2; ++dy)
#pragma unroll
                for (int dx = 0; dx < 2; ++dx) {
                    float y = ((float)acc[j][dy][dx][cc] * inv3 - sm[c]) * si[c] + sbe[c];
                    mm = fmaxf(mm, y);
                }
            a2[(size_t)b * 3136 + p * 64 + c] = quant2(mm);
        }
    }
}

// ---------------------------------------------------------------------------
// conv3 (64->64, 3x3, pad0, 7->5) + bn2 + clip + quant -> a3 [b][5][5][64] (= NHWC flat)
// ---------------------------------------------------------------------------
__global__ __launch_bounds__(256) void k_conv3(
    const unsigned char* __restrict__ a2, const char* __restrict__ w3s,
    const float* __restrict__ g2, const float* __restrict__ be2,
    const float* __restrict__ m2, const float* __restrict__ v2,
    unsigned char* __restrict__ a3) {
    __shared__ unsigned char sa[3136];         // [7][7][64]
    __shared__ char sw[64 * 592];
    __shared__ float sm[64], si[64], sbe[64];
    int b = blockIdx.x;
    int tid = threadIdx.x;
    {
        const uint4* src = (const uint4*)(a2 + (size_t)b * 3136);
        uint4* dst = (uint4*)sa;
        for (int i = tid; i < 196; i += 256) dst[i] = src[i];
        for (int u = tid; u < 2304; u += 256) {
            int c = u / 36, seg = u - c * 36;
            *(uint4*)(sw + c * 592 + seg * 16) =
                *(const uint4*)(w3s + c * 576 + seg * 16);
        }
        if (tid < 64) {
            sm[tid] = m2[tid];
            si[tid] = g2[tid] / sqrtf(v2[tid] + 1e-4f);
            sbe[tid] = be2[tid];
        }
    }
    __syncthreads();

    int c0 = tid & 31;
    int pg = tid >> 5;
    int oys[4], oxs[4];
#pragma unroll
    for (int j = 0; j < 4; ++j) {
        int p = pg + 8 * j;
        int oy = p / 5;
        oys[j] = (p < 25) ? oy : -1000;
        oxs[j] = p - oy * 5;
    }
    int acc[4][2];
#pragma unroll
    for (int j = 0; j < 4; ++j) { acc[j][0] = 0; acc[j][1] = 0; }

    for (int t = 0; t < 9; ++t) {
        int ky = t / 3, kx = t - ky * 3;
        uint4 wq0[4], wq1[4];
        {
            const uint4* wp0 = (const uint4*)(sw + c0 * 592 + t * 64);
            const uint4* wp1 = (const uint4*)(sw + (c0 + 32) * 592 + t * 64);
#pragma unroll
            for (int d = 0; d < 4; ++d) { wq0[d] = wp0[d]; wq1[d] = wp1[d]; }
        }
#pragma unroll
        for (int j = 0; j < 4; ++j) {
            if (oys[j] < 0) continue;
            int iy = oys[j] + ky;
            int ix = oxs[j] + kx;
            const uint4* ap = (const uint4*)(sa + (iy * 7 + ix) * 64);
            int s0 = acc[j][0], s1 = acc[j][1];
#pragma unroll
            for (int d = 0; d < 4; ++d) {
                uint4 av = ap[d];
                s0 = dot4i(av.x, wq0[d].x, s0);
                s0 = dot4i(av.y, wq0[d].y, s0);
                s0 = dot4i(av.z, wq0[d].z, s0);
                s0 = dot4i(av.w, wq0[d].w, s0);
                s1 = dot4i(av.x, wq1[d].x, s1);
                s1 = dot4i(av.y, wq1[d].y, s1);
                s1 = dot4i(av.z, wq1[d].z, s1);
                s1 = dot4i(av.w, wq1[d].w, s1);
            }
            acc[j][0] = s0;
            acc[j][1] = s1;
        }
    }

    const float inv3 = 1.f / 3.f;
#pragma unroll
    for (int j = 0; j < 4; ++j) {
        int p = pg + 8 * j;
        if (p >= 25) continue;
#pragma unroll
        for (int cc = 0; cc < 2; ++cc) {
            int c = c0 + 32 * cc;
            float y = ((float)acc[j][cc] * inv3 - sm[c]) * si[c] + sbe[c];
            a3[(size_t)b * 1600 + p * 64 + c] = quant2(y);
        }
    }
}

// ---------------------------------------------------------------------------
// fc1: h1[4096][512] = (a3[4096][1600] . sign(fw1)[512][1600]^T)/3 + fb1
// 64x64 tile per block, int8 dot, LDS stride 68 (conflict-free)
// ---------------------------------------------------------------------------
__global__ __launch_bounds__(256) void k_fc1(
    const unsigned char* __restrict__ a3, const char* __restrict__ fw1s,
    const float* __restrict__ fb1, float* __restrict__ h1) {
    __shared__ unsigned char sA[64 * 68];
    __shared__ char sW[64 * 68];
    int bb = (blockIdx.x >> 3) * 64;
    int ob = (blockIdx.x & 7) * 64;
    int tid = threadIdx.x;
    int tx = tid & 15, ty = tid >> 4;
    int row = tid >> 2, seg = tid & 3;
    int acc[4][4] = {};
    const unsigned char* aptr = a3 + (size_t)(bb + row) * 1600 + seg * 16;
    const char* wptr = fw1s + (size_t)(ob + row) * 1600 + seg * 16;

    for (int k0 = 0; k0 < 1600; k0 += 64) {
        uint4 av = *(const uint4*)(aptr + k0);
        uint4 wv = *(const uint4*)(wptr + k0);
        unsigned int* ad = (unsigned int*)(sA + row * 68 + seg * 16);
        ad[0] = av.x; ad[1] = av.y; ad[2] = av.z; ad[3] = av.w;
        unsigned int* wd = (unsigned int*)(sW + row * 68 + seg * 16);
        wd[0] = wv.x; wd[1] = wv.y; wd[2] = wv.z; wd[3] = wv.w;
        __syncthreads();
#pragma unroll
        for (int kk = 0; kk < 64; kk += 4) {
            unsigned int a4[4], w4[4];
#pragma unroll
            for (int r = 0; r < 4; ++r)
                a4[r] = *(const unsigned int*)(sA + (ty * 4 + r) * 68 + kk);
#pragma unroll
            for (int c = 0; c < 4; ++c)
                w4[c] = *(const unsigned int*)(sW + (tx * 4 + c) * 68 + kk);
#pragma unroll
            for (int r = 0; r < 4; ++r)
#pragma unroll
                for (int c = 0; c < 4; ++c)
                    acc[r][c] = dot4i(a4[r], w4[c], acc[r][c]);
        }
        __syncthreads();
    }

#pragma unroll
    for (int r = 0; r < 4; ++r)
#pragma unroll
        for (int c = 0; c < 4; ++c) {
            int o = ob + tx * 4 + c;
            h1[(size_t)(bb + ty * 4 + r) * 512 + o] =
                (float)acc[r][c] * (1.f / 3.f) + fb1[o];
        }
}

// ---------------------------------------------------------------------------
// fc2 + log_softmax: out[4096][10]
// one wave per batch row (4 rows per 256-thread block)
// ---------------------------------------------------------------------------
__global__ __launch_bounds__(256) void k_fc2(
    const float* __restrict__ h1, const float* __restrict__ fw2,
    const float* __restrict__ fb2, float* __restrict__ out) {
    __shared__ float sw[5120];
    __shared__ float sb[16];
    int tid = threadIdx.x;
    for (int i = tid; i < 5120; i += 256) sw[i] = fw2[i];
    if (tid < 10) sb[tid] = fb2[tid];
    __syncthreads();

    int wv = tid >> 6, lane = tid & 63;
    int b = blockIdx.x * 4 + wv;
    const float* hr = h1 + (size_t)b * 512;
    float p[10];
#pragma unroll
    for (int o = 0; o < 10; ++o) p[o] = 0.f;
    for (int k = lane; k < 512; k += 64) {
        float hv = hr[k];
#pragma unroll
        for (int o = 0; o < 10; ++o) p[o] += hv * sw[o * 512 + k];
    }
#pragma unroll
    for (int o = 0; o < 10; ++o) {
#pragma unroll
        for (int off = 32; off > 0; off >>= 1) p[o] += __shfl_xor(p[o], off, 64);
        p[o] += sb[o];
    }
    float mx = p[0];
#pragma unroll
    for (int o = 1; o < 10; ++o) mx = fmaxf(mx, p[o]);
    float se = 0.f;
#pragma unroll
    for (int o = 0; o < 10; ++o) se += expf(p[o] - mx);
    float lse = logf(se) + mx;
    float myv = 0.f;
#pragma unroll
    for (int o = 0; o < 10; ++o) myv = (lane == o) ? p[o] : myv;
    if (lane < 10) out[(size_t)b * 10 + lane] = myv - lse;
}

// ---------------------------------------------------------------------------
extern "C" void kernel_launch(void* const* d_in, const int* in_sizes, int n_in,
                              void* d_out, int out_size, void* d_ws, size_t ws_size,
                              hipStream_t stream) {
    const float* x   = (const float*)d_in[0];
    const float* w1  = (const float*)d_in[1];
    const float* b1  = (const float*)d_in[2];
    const float* w2  = (const float*)d_in[3];
    const float* g1  = (const float*)d_in[4];
    const float* be1 = (const float*)d_in[5];
    const float* m1  = (const float*)d_in[6];
    const float* v1  = (const float*)d_in[7];
    const float* w3  = (const float*)d_in[8];
    const float* g2  = (const float*)d_in[9];
    const float* be2 = (const float*)d_in[10];
    const float* m2  = (const float*)d_in[11];
    const float* v2  = (const float*)d_in[12];
    const float* fw1 = (const float*)d_in[13];
    const float* fb1 = (const float*)d_in[14];
    const float* fw2 = (const float*)d_in[15];
    const float* fb2 = (const float*)d_in[16];
    float* out = (float*)d_out;

    char* ws = (char*)d_ws;
    char* w2s  = ws;                                   // 36864
    char* w3s  = ws + 36864;                           // 36864
    char* fw1s = ws + 73728;                           // 819200
    unsigned char* a1 = (unsigned char*)(ws + 892928); // 4096*12544 = 51380224
    unsigned char* a2 = a1 + 51380224;                 // 4096*3136  = 12845056
    unsigned char* a3 = a2 + 12845056;                 // 4096*1600  = 6553600
    float* h1 = (float*)(void*)a1;                     // alias: a1 dead when fc1 runs

    k_signs<<<3200, 256, 0, stream>>>(w2, w3, fw1, w2s, w3s, fw1s);
    k_conv1<<<4096, 256, 0, stream>>>(x, w1, b1, a1);
    k_conv2<<<4096, 256, 0, stream>>>(a1, w2s, g1, be1, m1, v1, a2);
    k_conv3<<<4096, 256, 0, stream>>>(a2, w3s, g2, be2, m2, v2, a3);
    k_fc1<<<512, 256, 0, stream>>>(a3, fw1s, fb1, h1);
    k_fc2<<<1024, 256, 0, stream>>>(h1, fw2, fb2, out);
}

// Round 2
// 238.284 us; speedup vs baseline: 1.9326x; 1.9326x over previous
//
#include <hip/hip_runtime.h>

#define DEV __device__ __forceinline__

typedef int v4i __attribute__((ext_vector_type(4)));

#if __has_builtin(__builtin_amdgcn_sdot4)
DEV int dot4i(unsigned int a, unsigned int b, int c) {
    return __builtin_amdgcn_sdot4((int)a, (int)b, c, false);
}
#else
DEV int dot4i(unsigned int a, unsigned int b, int c) {
#pragma unroll
    for (int i = 0; i < 4; ++i) {
        c += (int)((signed char)((a >> (8 * i)) & 0xff)) *
             (int)((signed char)((b >> (8 * i)) & 0xff));
    }
    return c;
}
#endif

DEV unsigned char quant2(float y) {
    y = fminf(fmaxf(y, 0.f), 1.f);
    return (unsigned char)(int)rintf(y * 3.f);
}

DEV int imax(int a, int b) { return a > b ? a : b; }

// ---------------------------------------------------------------------------
// Sign precompute: w2/w3 [co][ci][3][3] -> s8 [co][t][ci] (t=ky*3+kx), fw1 -> s8
// ---------------------------------------------------------------------------
__global__ __launch_bounds__(256) void k_signs(
    const float* __restrict__ w2, const float* __restrict__ w3,
    const float* __restrict__ fw1,
    char* __restrict__ w2s, char* __restrict__ w3s, char* __restrict__ fw1s) {
    int i = blockIdx.x * 256 + threadIdx.x;
    if (i < 36864) {
        int co = i / 576, r = i - co * 576;
        int ci = r / 9, k = r - ci * 9;
        w2s[co * 576 + k * 64 + ci] = (w2[i] >= 0.f) ? 1 : -1;
        w3s[co * 576 + k * 64 + ci] = (w3[i] >= 0.f) ? 1 : -1;
    }
    if (i < 819200) fw1s[i] = (fw1[i] >= 0.f) ? 1 : -1;
}

// ---------------------------------------------------------------------------
// conv1 (1->64, 3x3, pad1) + bias + maxpool2 + clip + quant -> a1 [b][14][14][64] u8
// ---------------------------------------------------------------------------
__global__ __launch_bounds__(256) void k_conv1(
    const float* __restrict__ x, const float* __restrict__ w1f,
    const float* __restrict__ b1, unsigned char* __restrict__ a1) {
    __shared__ float sx[784];
    __shared__ float sw[576];
    __shared__ float sb[64];
    int b = blockIdx.x;
    int tid = threadIdx.x;
    for (int i = tid; i < 784; i += 256) sx[i] = x[(size_t)b * 784 + i];
    for (int i = tid; i < 576; i += 256) sw[i] = (w1f[i] >= 0.f) ? 1.f : -1.f;
    if (tid < 64) sb[tid] = b1[tid];
    __syncthreads();

    int cg = tid & 15;
    int pg = tid >> 4;

    float wv[4][9];
#pragma unroll
    for (int cc = 0; cc < 4; ++cc)
#pragma unroll
        for (int k = 0; k < 9; ++k) wv[cc][k] = sw[(cg * 4 + cc) * 9 + k];
    float bias[4];
#pragma unroll
    for (int cc = 0; cc < 4; ++cc) bias[cc] = sb[cg * 4 + cc];

    for (int p = pg; p < 196; p += 16) {
        int py = p / 14, px = p - py * 14;
        float xp[4][4];
#pragma unroll
        for (int r = 0; r < 4; ++r) {
            int iy = 2 * py - 1 + r;
#pragma unroll
            for (int s2 = 0; s2 < 4; ++s2) {
                int ix = 2 * px - 1 + s2;
                xp[r][s2] = ((unsigned)iy < 28u && (unsigned)ix < 28u)
                                ? sx[iy * 28 + ix] : 0.f;
            }
        }
        uchar4 ov;
        unsigned char oc[4];
#pragma unroll
        for (int cc = 0; cc < 4; ++cc) {
            float m = -1e30f;
#pragma unroll
            for (int dy = 0; dy < 2; ++dy)
#pragma unroll
                for (int dx = 0; dx < 2; ++dx) {
                    float s = 0.f;
#pragma unroll
                    for (int ky = 0; ky < 3; ++ky)
#pragma unroll
                        for (int kx = 0; kx < 3; ++kx)
                            s += wv[cc][ky * 3 + kx] * xp[dy + ky][dx + kx];
                    m = fmaxf(m, s);
                }
            oc[cc] = quant2(m + bias[cc]);
        }
        ov.x = oc[0]; ov.y = oc[1]; ov.z = oc[2]; ov.w = oc[3];
        *(uchar4*)(a1 + (size_t)b * 12544 + p * 64 + cg * 4) = ov;
    }
}

// ---------------------------------------------------------------------------
// conv2 via i8 MFMA: per image, im2col-free tap-GEMM.
//   A: padded act LDS [ck(4)][16x16 pix][16B]  (zero border)
//   B: weights LDS    [t(9)][ck(4)][co(64)][16B]
//   C 16x16 tiles: M=pixel (13 tiles over 196), N=co (4 tiles)
// bn + quant per conv pixel (quant commutes with maxpool), pool codes.
// ---------------------------------------------------------------------------
__global__ __launch_bounds__(256) void k_conv2_mfma(
    const unsigned char* __restrict__ a1, const char* __restrict__ w2s,
    const float* __restrict__ g1, const float* __restrict__ be1,
    const float* __restrict__ m1, const float* __restrict__ v1,
    unsigned char* __restrict__ a2) {
    __shared__ unsigned char sa[16384];      // [ck][256 pix][16]
    __shared__ char sw[36864];               // [t][ck][64 co][16]
    __shared__ unsigned char sq[64 * 208];   // [ch][208 pix] quant codes
    __shared__ float sm[64], si[64], sbe[64];
    int b = blockIdx.x, tid = threadIdx.x;
    {
        uint4 z = make_uint4(0, 0, 0, 0);
        uint4* zp = (uint4*)sa;
        for (int i = tid; i < 1024; i += 256) zp[i] = z;
    }
    __syncthreads();
    {
        const uint4* src = (const uint4*)(a1 + (size_t)b * 12544);
        for (int i = tid; i < 784; i += 256) {
            int pixel = i >> 2, ck = i & 3;
            int py = pixel / 14, px = pixel - py * 14;
            *(uint4*)(sa + ck * 4096 + ((py + 1) * 16 + px + 1) * 16) = src[i];
        }
        for (int u = tid; u < 2304; u += 256) {
            int co = u / 36, rem = u - co * 36;
            int t = rem >> 2, ck = rem & 3;
            *(uint4*)(sw + t * 4096 + ck * 1024 + co * 16) =
                *(const uint4*)(w2s + co * 576 + t * 64 + ck * 16);
        }
        if (tid < 64) {
            sm[tid] = m1[tid];
            si[tid] = g1[tid] * rsqrtf(v1[tid] + 1e-4f);
            sbe[tid] = be1[tid];
        }
    }
    __syncthreads();

    int w = tid >> 6, l = tid & 63;
    int lr = l & 15, lg = l >> 4;
    int abase[4], mts[4];
#pragma unroll
    for (int j = 0; j < 4; ++j) {
        int mt = w + 4 * j;
        mts[j] = mt;
        int p = mt * 16 + lr;
        if (p > 195) p = 195;
        int py = p / 14, px = p - py * 14;
        abase[j] = lg * 4096 + (py * 16 + px) * 16;  // top-left tap position
    }
    v4i acc[4][4] = {};
#pragma unroll
    for (int t = 0; t < 9; ++t) {
        int ky = t / 3, kx = t - ky * 3;
        int boff = t * 4096 + lg * 1024 + lr * 16;
        v4i bf[4];
#pragma unroll
        for (int nt = 0; nt < 4; ++nt)
            bf[nt] = *(const v4i*)(sw + boff + nt * 256);
        int aoff = (ky * 16 + kx) * 16;
#pragma unroll
        for (int j = 0; j < 4; ++j) {
            if (mts[j] < 13) {
                v4i af = *(const v4i*)(sa + abase[j] + aoff);
#pragma unroll
                for (int nt = 0; nt < 4; ++nt)
                    acc[j][nt] = __builtin_amdgcn_mfma_i32_16x16x64_i8(
                        af, bf[nt], acc[j][nt], 0, 0, 0);
            }
        }
    }

    const float inv3 = 1.f / 3.f;
#pragma unroll
    for (int j = 0; j < 4; ++j) {
        if (mts[j] < 13) {
#pragma unroll
            for (int nt = 0; nt < 4; ++nt) {
                int ch = nt * 16 + lr;
                float mu = sm[ch], sc = si[ch], bb = sbe[ch];
                unsigned int dw = 0;
#pragma unroll
                for (int r = 0; r < 4; ++r) {
                    float y = ((float)acc[j][nt][r] * inv3 - mu) * sc + bb;
                    dw |= (unsigned int)quant2(y) << (8 * r);
                }
                *(unsigned int*)(sq + ch * 208 + mts[j] * 16 + lg * 4) = dw;
            }
        }
    }
    __syncthreads();
    {
        unsigned char* outp = a2 + (size_t)b * 3136;
        for (int idx = tid; idx < 784; idx += 256) {
            int pp = idx >> 4, cg = idx & 15;
            int p00 = (pp / 7) * 28 + (pp % 7) * 2;
            unsigned int o = 0;
#pragma unroll
            for (int cc = 0; cc < 4; ++cc) {
                const unsigned char* q = sq + (cg * 4 + cc) * 208 + p00;
                int mx = imax(imax(q[0], q[1]), imax(q[14], q[15]));
                o |= (unsigned int)mx << (8 * cc);
            }
            *(unsigned int*)(outp + idx * 4) = o;
        }
    }
}

// ---------------------------------------------------------------------------
// conv3 via i8 MFMA: 4 images per block (amortize 36KB weight stage),
// wave w owns image w. pad0: input [7][7][64] staged as [ck][49 pix][16B].
// M = 25 out pixels (2 tiles), N = 64 (4 tiles). bn + quant, no pool.
// ---------------------------------------------------------------------------
__global__ __launch_bounds__(256) void k_conv3_mfma(
    const unsigned char* __restrict__ a2, const char* __restrict__ w3s,
    const float* __restrict__ g2, const float* __restrict__ be2,
    const float* __restrict__ m2, const float* __restrict__ v2,
    unsigned char* __restrict__ a3) {
    __shared__ unsigned char sa[4 * 3136];   // [img][ck][49][16]
    __shared__ char sw[36864];               // [t][ck][64 co][16]
    __shared__ unsigned char so[4 * 2560];   // [img][32 pix][80]
    __shared__ float sm[64], si[64], sbe[64];
    int b0 = blockIdx.x * 4, tid = threadIdx.x;
    {
        const uint4* src = (const uint4*)(a2 + (size_t)b0 * 3136);
        for (int i = tid; i < 784; i += 256) {
            int img = i / 196, r = i - img * 196;
            int pixel = r >> 2, ck = r & 3;
            *(uint4*)(sa + img * 3136 + ck * 784 + pixel * 16) = src[i];
        }
        for (int u = tid; u < 2304; u += 256) {
            int co = u / 36, rem = u - co * 36;
            int t = rem >> 2, ck = rem & 3;
            *(uint4*)(sw + t * 4096 + ck * 1024 + co * 16) =
                *(const uint4*)(w3s + co * 576 + t * 64 + ck * 16);
        }
        if (tid < 64) {
            sm[tid] = m2[tid];
            si[tid] = g2[tid] * rsqrtf(v2[tid] + 1e-4f);
            sbe[tid] = be2[tid];
        }
    }
    __syncthreads();

    int w = tid >> 6, l = tid & 63;
    int lr = l & 15, lg = l >> 4;
    const unsigned char* sai = sa + w * 3136;
    int abase[2];
#pragma unroll
    for (int mt = 0; mt < 2; ++mt) {
        int p = mt * 16 + lr;
        if (p > 24) p = 24;
        int oy = p / 5, ox = p - oy * 5;
        abase[mt] = lg * 784 + (oy * 7 + ox) * 16;
    }
    v4i acc[2][4] = {};
#pragma unroll
    for (int t = 0; t < 9; ++t) {
        int ky = t / 3, kx = t - ky * 3;
        int boff = t * 4096 + lg * 1024 + lr * 16;
        v4i bf[4];
#pragma unroll
        for (int nt = 0; nt < 4; ++nt)
            bf[nt] = *(const v4i*)(sw + boff + nt * 256);
        int aoff = (ky * 7 + kx) * 16;
#pragma unroll
        for (int mt = 0; mt < 2; ++mt) {
            v4i af = *(const v4i*)(sai + abase[mt] + aoff);
#pragma unroll
            for (int nt = 0; nt < 4; ++nt)
                acc[mt][nt] = __builtin_amdgcn_mfma_i32_16x16x64_i8(
                    af, bf[nt], acc[mt][nt], 0, 0, 0);
        }
    }

    unsigned char* soi = so + w * 2560;
    const float inv3 = 1.f / 3.f;
#pragma unroll
    for (int mt = 0; mt < 2; ++mt)
#pragma unroll
        for (int nt = 0; nt < 4; ++nt) {
            int ch = nt * 16 + lr;
            float mu = sm[ch], sc = si[ch], bb = sbe[ch];
#pragma unroll
            for (int r = 0; r < 4; ++r) {
                int pixel = mt * 16 + lg * 4 + r;
                float y = ((float)acc[mt][nt][r] * inv3 - mu) * sc + bb;
                soi[pixel * 80 + ch] = quant2(y);
            }
        }
    __syncthreads();
    for (int idx = tid; idx < 400; idx += 256) {
        int img = idx / 100, r = idx - img * 100;
        int p = r >> 2, c0 = r & 3;
        *(uint4*)(a3 + (size_t)(b0 + img) * 1600 + r * 16) =
            *(const uint4*)(so + img * 2560 + p * 80 + c0 * 16);
    }
}

// ---------------------------------------------------------------------------
// fc1: h1[4096][512] = (a3[4096][1600] . sign(fw1)[512][1600]^T)/3 + fb1
// ---------------------------------------------------------------------------
__global__ __launch_bounds__(256) void k_fc1(
    const unsigned char* __restrict__ a3, const char* __restrict__ fw1s,
    const float* __restrict__ fb1, float* __restrict__ h1) {
    __shared__ unsigned char sA[64 * 68];
    __shared__ char sW[64 * 68];
    int bb = (blockIdx.x >> 3) * 64;
    int ob = (blockIdx.x & 7) * 64;
    int tid = threadIdx.x;
    int tx = tid & 15, ty = tid >> 4;
    int row = tid >> 2, seg = tid & 3;
    int acc[4][4] = {};
    const unsigned char* aptr = a3 + (size_t)(bb + row) * 1600 + seg * 16;
    const char* wptr = fw1s + (size_t)(ob + row) * 1600 + seg * 16;

    for (int k0 = 0; k0 < 1600; k0 += 64) {
        uint4 av = *(const uint4*)(aptr + k0);
        uint4 wv = *(const uint4*)(wptr + k0);
        unsigned int* ad = (unsigned int*)(sA + row * 68 + seg * 16);
        ad[0] = av.x; ad[1] = av.y; ad[2] = av.z; ad[3] = av.w;
        unsigned int* wd = (unsigned int*)(sW + row * 68 + seg * 16);
        wd[0] = wv.x; wd[1] = wv.y; wd[2] = wv.z; wd[3] = wv.w;
        __syncthreads();
#pragma unroll
        for (int kk = 0; kk < 64; kk += 4) {
            unsigned int a4[4], w4[4];
#pragma unroll
            for (int r = 0; r < 4; ++r)
                a4[r] = *(const unsigned int*)(sA + (ty * 4 + r) * 68 + kk);
#pragma unroll
            for (int c = 0; c < 4; ++c)
                w4[c] = *(const unsigned int*)(sW + (tx * 4 + c) * 68 + kk);
#pragma unroll
            for (int r = 0; r < 4; ++r)
#pragma unroll
                for (int c = 0; c < 4; ++c)
                    acc[r][c] = dot4i(a4[r], w4[c], acc[r][c]);
        }
        __syncthreads();
    }

#pragma unroll
    for (int r = 0; r < 4; ++r)
#pragma unroll
        for (int c = 0; c < 4; ++c) {
            int o = ob + tx * 4 + c;
            h1[(size_t)(bb + ty * 4 + r) * 512 + o] =
                (float)acc[r][c] * (1.f / 3.f) + fb1[o];
        }
}

// ---------------------------------------------------------------------------
// fc2 + log_softmax: out[4096][10]
// ---------------------------------------------------------------------------
__global__ __launch_bounds__(256) void k_fc2(
    const float* __restrict__ h1, const float* __restrict__ fw2,
    const float* __restrict__ fb2, float* __restrict__ out) {
    __shared__ float sw[5120];
    __shared__ float sb[16];
    int tid = threadIdx.x;
    for (int i = tid; i < 5120; i += 256) sw[i] = fw2[i];
    if (tid < 10) sb[tid] = fb2[tid];
    __syncthreads();

    int wv = tid >> 6, lane = tid & 63;
    int b = blockIdx.x * 4 + wv;
    const float* hr = h1 + (size_t)b * 512;
    float p[10];
#pragma unroll
    for (int o = 0; o < 10; ++o) p[o] = 0.f;
    for (int k = lane; k < 512; k += 64) {
        float hv = hr[k];
#pragma unroll
        for (int o = 0; o < 10; ++o) p[o] += hv * sw[o * 512 + k];
    }
#pragma unroll
    for (int o = 0; o < 10; ++o) {
#pragma unroll
        for (int off = 32; off > 0; off >>= 1) p[o] += __shfl_xor(p[o], off, 64);
        p[o] += sb[o];
    }
    float mx = p[0];
#pragma unroll
    for (int o = 1; o < 10; ++o) mx = fmaxf(mx, p[o]);
    float se = 0.f;
#pragma unroll
    for (int o = 0; o < 10; ++o) se += expf(p[o] - mx);
    float lse = logf(se) + mx;
    float myv = 0.f;
#pragma unroll
    for (int o = 0; o < 10; ++o) myv = (lane == o) ? p[o] : myv;
    if (lane < 10) out[(size_t)b * 10 + lane] = myv - lse;
}

// ---------------------------------------------------------------------------
extern "C" void kernel_launch(void* const* d_in, const int* in_sizes, int n_in,
                              void* d_out, int out_size, void* d_ws, size_t ws_size,
                              hipStream_t stream) {
    const float* x   = (const float*)d_in[0];
    const float* w1  = (const float*)d_in[1];
    const float* b1  = (const float*)d_in[2];
    const float* w2  = (const float*)d_in[3];
    const float* g1  = (const float*)d_in[4];
    const float* be1 = (const float*)d_in[5];
    const float* m1  = (const float*)d_in[6];
    const float* v1  = (const float*)d_in[7];
    const float* w3  = (const float*)d_in[8];
    const float* g2  = (const float*)d_in[9];
    const float* be2 = (const float*)d_in[10];
    const float* m2  = (const float*)d_in[11];
    const float* v2  = (const float*)d_in[12];
    const float* fw1 = (const float*)d_in[13];
    const float* fb1 = (const float*)d_in[14];
    const float* fw2 = (const float*)d_in[15];
    const float* fb2 = (const float*)d_in[16];
    float* out = (float*)d_out;

    char* ws = (char*)d_ws;
    char* w2s  = ws;                                   // 36864
    char* w3s  = ws + 36864;                           // 36864
    char* fw1s = ws + 73728;                           // 819200
    unsigned char* a1 = (unsigned char*)(ws + 892928); // 4096*12544 = 51380224
    unsigned char* a2 = a1 + 51380224;                 // 4096*3136  = 12845056
    unsigned char* a3 = a2 + 12845056;                 // 4096*1600  = 6553600
    float* h1 = (float*)(void*)a1;                     // alias: a1 dead when fc1 runs

    k_signs<<<3200, 256, 0, stream>>>(w2, w3, fw1, w2s, w3s, fw1s);
    k_conv1<<<4096, 256, 0, stream>>>(x, w1, b1, a1);
    k_conv2_mfma<<<4096, 256, 0, stream>>>(a1, w2s, g1, be1, m1, v1, a2);
    k_conv3_mfma<<<1024, 256, 0, stream>>>(a2, w3s, g2, be2, m2, v2, a3);
    k_fc1<<<512, 256, 0, stream>>>(a3, fw1s, fb1, h1);
    k_fc2<<<1024, 256, 0, stream>>>(h1, fw2, fb2, out);
}

// Round 3
// 166.633 us; speedup vs baseline: 2.7636x; 1.4300x over previous
//
#include <hip/hip_runtime.h>

#define DEV __device__ __forceinline__

typedef int v4i __attribute__((ext_vector_type(4)));

#if __has_builtin(__builtin_amdgcn_sdot4)
DEV int dot4i(unsigned int a, unsigned int b, int c) {
    return __builtin_amdgcn_sdot4((int)a, (int)b, c, false);
}
#else
DEV int dot4i(unsigned int a, unsigned int b, int c) {
#pragma unroll
    for (int i = 0; i < 4; ++i) {
        c += (int)((signed char)((a >> (8 * i)) & 0xff)) *
             (int)((signed char)((b >> (8 * i)) & 0xff));
    }
    return c;
}
#endif

// quantize pre-scaled y3 = 3*y: clamp to [0,3], round-to-even
DEV unsigned int quant3(float y3) {
    return (unsigned int)(int)rintf(fminf(fmaxf(y3, 0.f), 3.f));
}

DEV int imax(int a, int b) { return a > b ? a : b; }

// ---------------------------------------------------------------------------
// Sign precompute: w2/w3 [co][ci][3][3] -> s8 [co][t][ci] (t=ky*3+kx), fw1 -> s8
// ---------------------------------------------------------------------------
__global__ __launch_bounds__(256) void k_signs(
    const float* __restrict__ w2, const float* __restrict__ w3,
    const float* __restrict__ fw1,
    char* __restrict__ w2s, char* __restrict__ w3s, char* __restrict__ fw1s) {
    int i = blockIdx.x * 256 + threadIdx.x;
    if (i < 36864) {
        int co = i / 576, r = i - co * 576;
        int ci = r / 9, k = r - ci * 9;
        w2s[co * 576 + k * 64 + ci] = (w2[i] >= 0.f) ? 1 : -1;
        w3s[co * 576 + k * 64 + ci] = (w3[i] >= 0.f) ? 1 : -1;
    }
    if (i < 819200) fw1s[i] = (fw1[i] >= 0.f) ? 1 : -1;
}

// ---------------------------------------------------------------------------
// conv1 (1->64, 3x3, pad1) + bias + maxpool2 + clip + quant -> a1 [b][196][64] u8
// 1 image/block. pg = tid>>4 -> pool row (0..13), cg = tid&15 -> 4 channels.
// Padded 30x33 LDS image (zero border, stride 33 = conflict-free rows).
// Sliding 4x4 window: 8 new LDS reads per pool pixel.
// __launch_bounds__(256,4): 128-VGPR budget so the 36 weights stay in regs.
// ---------------------------------------------------------------------------
__global__ __launch_bounds__(256, 4) void k_conv1(
    const float* __restrict__ x, const float* __restrict__ w1f,
    const float* __restrict__ b1, unsigned char* __restrict__ a1) {
    __shared__ float sxp[30][33];
    __shared__ float sw[576];
    __shared__ float sb3[64];
    int b = blockIdx.x, tid = threadIdx.x;
    float* sf = &sxp[0][0];
    for (int i = tid; i < 990; i += 256) sf[i] = 0.f;
    for (int i = tid; i < 576; i += 256) sw[i] = (w1f[i] >= 0.f) ? 1.f : -1.f;
    if (tid < 64) sb3[tid] = 3.f * b1[tid];
    __syncthreads();
    for (int i = tid; i < 784; i += 256) {
        int iy = i / 28, ix = i - iy * 28;
        sxp[iy + 1][ix + 1] = x[(size_t)b * 784 + i];
    }
    __syncthreads();

    int cg = tid & 15, pg = tid >> 4;
    float w[4][9], bias3[4];
#pragma unroll
    for (int cc = 0; cc < 4; ++cc) {
#pragma unroll
        for (int k = 0; k < 9; ++k) w[cc][k] = sw[(cg * 4 + cc) * 9 + k];
        bias3[cc] = sb3[cg * 4 + cc];
    }
    if (pg >= 14) return;

    int r0 = pg * 2;
    float xw[4][4];
#pragma unroll
    for (int r = 0; r < 4; ++r)
#pragma unroll
        for (int s = 0; s < 4; ++s) xw[r][s] = sxp[r0 + r][s];

    unsigned char* orow = a1 + (size_t)b * 12544 + (pg * 14) * 64 + cg * 4;
#pragma unroll
    for (int px = 0; px < 14; ++px) {
        unsigned int dw = 0;
#pragma unroll
        for (int cc = 0; cc < 4; ++cc) {
            float mx = 0.f;
#pragma unroll
            for (int dy = 0; dy < 2; ++dy)
#pragma unroll
                for (int dx = 0; dx < 2; ++dx) {
                    float s = w[cc][0] * xw[dy][dx];
#pragma unroll
                    for (int k = 1; k < 9; ++k)
                        s = fmaf(w[cc][k], xw[dy + k / 3][dx + k - (k / 3) * 3], s);
                    mx = (dy == 0 && dx == 0) ? s : fmaxf(mx, s);
                }
            float y3 = fmaf(mx, 3.f, bias3[cc]);
            dw |= quant3(y3) << (8 * cc);
        }
        *(unsigned int*)(orow + px * 64) = dw;
        if (px < 13) {
#pragma unroll
            for (int r = 0; r < 4; ++r) {
                xw[r][0] = xw[r][2];
                xw[r][1] = xw[r][3];
                xw[r][2] = sxp[r0 + r][2 * px + 4];
                xw[r][3] = sxp[r0 + r][2 * px + 5];
            }
        }
    }
}

// ---------------------------------------------------------------------------
// conv2 via i8 MFMA (as round 2, epilogue folded to 1 FMA affine)
// ---------------------------------------------------------------------------
__global__ __launch_bounds__(256) void k_conv2_mfma(
    const unsigned char* __restrict__ a1, const char* __restrict__ w2s,
    const float* __restrict__ g1, const float* __restrict__ be1,
    const float* __restrict__ m1, const float* __restrict__ v1,
    unsigned char* __restrict__ a2) {
    __shared__ unsigned char sa[16384];      // [ck][256 pix][16]
    __shared__ char sw[36864];               // [t][ck][64 co][16]
    __shared__ unsigned char sq[64 * 208];   // [ch][208 pix] quant codes
    __shared__ float ssc[64], sof[64];
    int b = blockIdx.x, tid = threadIdx.x;
    {
        uint4 z = make_uint4(0, 0, 0, 0);
        uint4* zp = (uint4*)sa;
        for (int i = tid; i < 1024; i += 256) zp[i] = z;
    }
    __syncthreads();
    {
        const uint4* src = (const uint4*)(a1 + (size_t)b * 12544);
        for (int i = tid; i < 784; i += 256) {
            int pixel = i >> 2, ck = i & 3;
            int py = pixel / 14, px = pixel - py * 14;
            *(uint4*)(sa + ck * 4096 + ((py + 1) * 16 + px + 1) * 16) = src[i];
        }
        for (int u = tid; u < 2304; u += 256) {
            int co = u / 36, rem = u - co * 36;
            int t = rem >> 2, ck = rem & 3;
            *(uint4*)(sw + t * 4096 + ck * 1024 + co * 16) =
                *(const uint4*)(w2s + co * 576 + t * 64 + ck * 16);
        }
        if (tid < 64) {
            float si = g1[tid] * rsqrtf(v1[tid] + 1e-4f);
            ssc[tid] = si;                                // (1/3)*si*3
            sof[tid] = 3.f * (be1[tid] - m1[tid] * si);
        }
    }
    __syncthreads();

    int w = tid >> 6, l = tid & 63;
    int lr = l & 15, lg = l >> 4;
    int abase[4], mts[4];
#pragma unroll
    for (int j = 0; j < 4; ++j) {
        int mt = w + 4 * j;
        mts[j] = mt;
        int p = mt * 16 + lr;
        if (p > 195) p = 195;
        int py = p / 14, px = p - py * 14;
        abase[j] = lg * 4096 + (py * 16 + px) * 16;
    }
    v4i acc[4][4] = {};
#pragma unroll
    for (int t = 0; t < 9; ++t) {
        int ky = t / 3, kx = t - ky * 3;
        int boff = t * 4096 + lg * 1024 + lr * 16;
        v4i bf[4];
#pragma unroll
        for (int nt = 0; nt < 4; ++nt)
            bf[nt] = *(const v4i*)(sw + boff + nt * 256);
        int aoff = (ky * 16 + kx) * 16;
#pragma unroll
        for (int j = 0; j < 4; ++j) {
            if (mts[j] < 13) {
                v4i af = *(const v4i*)(sa + abase[j] + aoff);
#pragma unroll
                for (int nt = 0; nt < 4; ++nt)
                    acc[j][nt] = __builtin_amdgcn_mfma_i32_16x16x64_i8(
                        af, bf[nt], acc[j][nt], 0, 0, 0);
            }
        }
    }

#pragma unroll
    for (int j = 0; j < 4; ++j) {
        if (mts[j] < 13) {
#pragma unroll
            for (int nt = 0; nt < 4; ++nt) {
                int ch = nt * 16 + lr;
                float sc = ssc[ch], of = sof[ch];
                unsigned int dw = 0;
#pragma unroll
                for (int r = 0; r < 4; ++r)
                    dw |= quant3(fmaf((float)acc[j][nt][r], sc, of)) << (8 * r);
                *(unsigned int*)(sq + ch * 208 + mts[j] * 16 + lg * 4) = dw;
            }
        }
    }
    __syncthreads();
    {
        unsigned char* outp = a2 + (size_t)b * 3136;
        for (int idx = tid; idx < 784; idx += 256) {
            int pp = idx >> 4, cg = idx & 15;
            int p00 = (pp / 7) * 28 + (pp % 7) * 2;
            unsigned int o = 0;
#pragma unroll
            for (int cc = 0; cc < 4; ++cc) {
                const unsigned char* q = sq + (cg * 4 + cc) * 208 + p00;
                int mx = imax(imax(q[0], q[1]), imax(q[14], q[15]));
                o |= (unsigned int)mx << (8 * cc);
            }
            *(unsigned int*)(outp + idx * 4) = o;
        }
    }
}

// ---------------------------------------------------------------------------
// conv3 via i8 MFMA: 4 images per block (as round 2, folded epilogue)
// ---------------------------------------------------------------------------
__global__ __launch_bounds__(256) void k_conv3_mfma(
    const unsigned char* __restrict__ a2, const char* __restrict__ w3s,
    const float* __restrict__ g2, const float* __restrict__ be2,
    const float* __restrict__ m2, const float* __restrict__ v2,
    unsigned char* __restrict__ a3) {
    __shared__ unsigned char sa[4 * 3136];   // [img][ck][49][16]
    __shared__ char sw[36864];               // [t][ck][64 co][16]
    __shared__ unsigned char so[4 * 2560];   // [img][32 pix][80]
    __shared__ float ssc[64], sof[64];
    int b0 = blockIdx.x * 4, tid = threadIdx.x;
    {
        const uint4* src = (const uint4*)(a2 + (size_t)b0 * 3136);
        for (int i = tid; i < 784; i += 256) {
            int img = i / 196, r = i - img * 196;
            int pixel = r >> 2, ck = r & 3;
            *(uint4*)(sa + img * 3136 + ck * 784 + pixel * 16) = src[i];
        }
        for (int u = tid; u < 2304; u += 256) {
            int co = u / 36, rem = u - co * 36;
            int t = rem >> 2, ck = rem & 3;
            *(uint4*)(sw + t * 4096 + ck * 1024 + co * 16) =
                *(const uint4*)(w3s + co * 576 + t * 64 + ck * 16);
        }
        if (tid < 64) {
            float si = g2[tid] * rsqrtf(v2[tid] + 1e-4f);
            ssc[tid] = si;
            sof[tid] = 3.f * (be2[tid] - m2[tid] * si);
        }
    }
    __syncthreads();

    int w = tid >> 6, l = tid & 63;
    int lr = l & 15, lg = l >> 4;
    const unsigned char* sai = sa + w * 3136;
    int abase[2];
#pragma unroll
    for (int mt = 0; mt < 2; ++mt) {
        int p = mt * 16 + lr;
        if (p > 24) p = 24;
        int oy = p / 5, ox = p - oy * 5;
        abase[mt] = lg * 784 + (oy * 7 + ox) * 16;
    }
    v4i acc[2][4] = {};
#pragma unroll
    for (int t = 0; t < 9; ++t) {
        int ky = t / 3, kx = t - ky * 3;
        int boff = t * 4096 + lg * 1024 + lr * 16;
        v4i bf[4];
#pragma unroll
        for (int nt = 0; nt < 4; ++nt)
            bf[nt] = *(const v4i*)(sw + boff + nt * 256);
        int aoff = (ky * 7 + kx) * 16;
#pragma unroll
        for (int mt = 0; mt < 2; ++mt) {
            v4i af = *(const v4i*)(sai + abase[mt] + aoff);
#pragma unroll
            for (int nt = 0; nt < 4; ++nt)
                acc[mt][nt] = __builtin_amdgcn_mfma_i32_16x16x64_i8(
                    af, bf[nt], acc[mt][nt], 0, 0, 0);
        }
    }

    unsigned char* soi = so + w * 2560;
#pragma unroll
    for (int mt = 0; mt < 2; ++mt)
#pragma unroll
        for (int nt = 0; nt < 4; ++nt) {
            int ch = nt * 16 + lr;
            float sc = ssc[ch], of = sof[ch];
#pragma unroll
            for (int r = 0; r < 4; ++r) {
                int pixel = mt * 16 + lg * 4 + r;
                soi[pixel * 80 + ch] =
                    (unsigned char)quant3(fmaf((float)acc[mt][nt][r], sc, of));
            }
        }
    __syncthreads();
    for (int idx = tid; idx < 400; idx += 256) {
        int img = idx / 100, r = idx - img * 100;
        int p = r >> 2, c0 = r & 3;
        *(uint4*)(a3 + (size_t)(b0 + img) * 1600 + r * 16) =
            *(const uint4*)(so + img * 2560 + p * 80 + c0 * 16);
    }
}

// ---------------------------------------------------------------------------
// fc1 via i8 MFMA: h1[4096][512] = (a3 . fw1s^T)/3 + fb1
// 64x64 tile/block, 4 waves in 2x2 grid, K=1600 in 25 steps of 64.
// LDS rows stride 80B (2-way max on ds_read_b128). Register prefetch of
// next K-chunk overlaps global latency with MFMA (T14).
// ---------------------------------------------------------------------------
__global__ __launch_bounds__(256) void k_fc1_mfma(
    const unsigned char* __restrict__ a3, const char* __restrict__ fw1s,
    const float* __restrict__ fb1, float* __restrict__ h1) {
    __shared__ unsigned char sA[64 * 80];
    __shared__ unsigned char sB[64 * 80];
    __shared__ float sbias[64];
    int bb = (blockIdx.x >> 3) * 64;
    int ob = (blockIdx.x & 7) * 64;
    int tid = threadIdx.x;
    int row = tid >> 2, seg = tid & 3;
    if (tid < 64) sbias[tid] = fb1[ob + tid];
    const unsigned char* Ag = a3 + (size_t)(bb + row) * 1600 + seg * 16;
    const char* Bg = fw1s + (size_t)(ob + row) * 1600 + seg * 16;
    uint4 av = *(const uint4*)Ag;
    uint4 bv = *(const uint4*)Bg;

    int w = tid >> 6, l = tid & 63;
    int wm = w >> 1, wn = w & 1;
    int lr = l & 15, lg = l >> 4;
    const unsigned char* sAr = sA + (wm * 32 + lr) * 80 + lg * 16;
    const unsigned char* sBr = sB + (wn * 32 + lr) * 80 + lg * 16;
    v4i acc[2][2] = {};

    for (int k0 = 0; k0 < 1600; k0 += 64) {
        *(uint4*)(sA + row * 80 + seg * 16) = av;
        *(uint4*)(sB + row * 80 + seg * 16) = bv;
        __syncthreads();
        if (k0 < 1536) {
            av = *(const uint4*)(Ag + k0 + 64);
            bv = *(const uint4*)(Bg + k0 + 64);
        }
        v4i af0 = *(const v4i*)(sAr);
        v4i af1 = *(const v4i*)(sAr + 16 * 80);
        v4i bf0 = *(const v4i*)(sBr);
        v4i bf1 = *(const v4i*)(sBr + 16 * 80);
        acc[0][0] = __builtin_amdgcn_mfma_i32_16x16x64_i8(af0, bf0, acc[0][0], 0, 0, 0);
        acc[0][1] = __builtin_amdgcn_mfma_i32_16x16x64_i8(af0, bf1, acc[0][1], 0, 0, 0);
        acc[1][0] = __builtin_amdgcn_mfma_i32_16x16x64_i8(af1, bf0, acc[1][0], 0, 0, 0);
        acc[1][1] = __builtin_amdgcn_mfma_i32_16x16x64_i8(af1, bf1, acc[1][1], 0, 0, 0);
        __syncthreads();
    }

    const float inv3 = 1.f / 3.f;
#pragma unroll
    for (int mt = 0; mt < 2; ++mt)
#pragma unroll
        for (int nt = 0; nt < 2; ++nt) {
            int gcol = ob + wn * 32 + nt * 16 + lr;
            float bias = sbias[wn * 32 + nt * 16 + lr];
#pragma unroll
            for (int r = 0; r < 4; ++r) {
                int grow = bb + wm * 32 + mt * 16 + lg * 4 + r;
                h1[(size_t)grow * 512 + gcol] = (float)acc[mt][nt][r] * inv3 + bias;
            }
        }
}

// ---------------------------------------------------------------------------
// fc2 + log_softmax: out[4096][10]
// ---------------------------------------------------------------------------
__global__ __launch_bounds__(256) void k_fc2(
    const float* __restrict__ h1, const float* __restrict__ fw2,
    const float* __restrict__ fb2, float* __restrict__ out) {
    __shared__ float sw[5120];
    __shared__ float sb[16];
    int tid = threadIdx.x;
    for (int i = tid; i < 5120; i += 256) sw[i] = fw2[i];
    if (tid < 10) sb[tid] = fb2[tid];
    __syncthreads();

    int wv = tid >> 6, lane = tid & 63;
    int b = blockIdx.x * 4 + wv;
    const float* hr = h1 + (size_t)b * 512;
    float p[10];
#pragma unroll
    for (int o = 0; o < 10; ++o) p[o] = 0.f;
    for (int k = lane; k < 512; k += 64) {
        float hv = hr[k];
#pragma unroll
        for (int o = 0; o < 10; ++o) p[o] += hv * sw[o * 512 + k];
    }
#pragma unroll
    for (int o = 0; o < 10; ++o) {
#pragma unroll
        for (int off = 32; off > 0; off >>= 1) p[o] += __shfl_xor(p[o], off, 64);
        p[o] += sb[o];
    }
    float mx = p[0];
#pragma unroll
    for (int o = 1; o < 10; ++o) mx = fmaxf(mx, p[o]);
    float se = 0.f;
#pragma unroll
    for (int o = 0; o < 10; ++o) se += expf(p[o] - mx);
    float lse = logf(se) + mx;
    float myv = 0.f;
#pragma unroll
    for (int o = 0; o < 10; ++o) myv = (lane == o) ? p[o] : myv;
    if (lane < 10) out[(size_t)b * 10 + lane] = myv - lse;
}

// ---------------------------------------------------------------------------
extern "C" void kernel_launch(void* const* d_in, const int* in_sizes, int n_in,
                              void* d_out, int out_size, void* d_ws, size_t ws_size,
                              hipStream_t stream) {
    const float* x   = (const float*)d_in[0];
    const float* w1  = (const float*)d_in[1];
    const float* b1  = (const float*)d_in[2];
    const float* w2  = (const float*)d_in[3];
    const float* g1  = (const float*)d_in[4];
    const float* be1 = (const float*)d_in[5];
    const float* m1  = (const float*)d_in[6];
    const float* v1  = (const float*)d_in[7];
    const float* w3  = (const float*)d_in[8];
    const float* g2  = (const float*)d_in[9];
    const float* be2 = (const float*)d_in[10];
    const float* m2  = (const float*)d_in[11];
    const float* v2  = (const float*)d_in[12];
    const float* fw1 = (const float*)d_in[13];
    const float* fb1 = (const float*)d_in[14];
    const float* fw2 = (const float*)d_in[15];
    const float* fb2 = (const float*)d_in[16];
    float* out = (float*)d_out;

    char* ws = (char*)d_ws;
    char* w2s  = ws;                                   // 36864
    char* w3s  = ws + 36864;                           // 36864
    char* fw1s = ws + 73728;                           // 819200
    unsigned char* a1 = (unsigned char*)(ws + 892928); // 4096*12544 = 51380224
    unsigned char* a2 = a1 + 51380224;                 // 4096*3136  = 12845056
    unsigned char* a3 = a2 + 12845056;                 // 4096*1600  = 6553600
    float* h1 = (float*)(void*)a1;                     // alias: a1 dead when fc1 runs

    k_signs<<<3200, 256, 0, stream>>>(w2, w3, fw1, w2s, w3s, fw1s);
    k_conv1<<<4096, 256, 0, stream>>>(x, w1, b1, a1);
    k_conv2_mfma<<<4096, 256, 0, stream>>>(a1, w2s, g1, be1, m1, v1, a2);
    k_conv3_mfma<<<1024, 256, 0, stream>>>(a2, w3s, g2, be2, m2, v2, a3);
    k_fc1_mfma<<<512, 256, 0, stream>>>(a3, fw1s, fb1, h1);
    k_fc2<<<1024, 256, 0, stream>>>(h1, fw2, fb2, out);
}

// Round 4
// 143.764 us; speedup vs baseline: 3.2032x; 1.1591x over previous
//
#include <hip/hip_runtime.h>

#define DEV __device__ __forceinline__

typedef int v4i __attribute__((ext_vector_type(4)));

#if __has_builtin(__builtin_amdgcn_sdot4)
DEV int dot4i(unsigned int a, unsigned int b, int c) {
    return __builtin_amdgcn_sdot4((int)a, (int)b, c, false);
}
#else
DEV int dot4i(unsigned int a, unsigned int b, int c) {
#pragma unroll
    for (int i = 0; i < 4; ++i) {
        c += (int)((signed char)((a >> (8 * i)) & 0xff)) *
             (int)((signed char)((b >> (8 * i)) & 0xff));
    }
    return c;
}
#endif

// quantize pre-scaled y3 = 3*y: clamp to [0,3], round-to-even
DEV unsigned int quant3(float y3) {
    return (unsigned int)(int)rintf(fminf(fmaxf(y3, 0.f), 3.f));
}

DEV int imax(int a, int b) { return a > b ? a : b; }
DEV int imin(int a, int b) { return a < b ? a : b; }

// ---------------------------------------------------------------------------
// Sign precompute: w2/w3 [co][ci][3][3] -> s8 [co][t][ci] (t=ky*3+kx), fw1 -> s8
// ---------------------------------------------------------------------------
__global__ __launch_bounds__(256) void k_signs(
    const float* __restrict__ w2, const float* __restrict__ w3,
    const float* __restrict__ fw1,
    char* __restrict__ w2s, char* __restrict__ w3s, char* __restrict__ fw1s) {
    int i = blockIdx.x * 256 + threadIdx.x;
    if (i < 36864) {
        int co = i / 576, r = i - co * 576;
        int ci = r / 9, k = r - ci * 9;
        w2s[co * 576 + k * 64 + ci] = (w2[i] >= 0.f) ? 1 : -1;
        w3s[co * 576 + k * 64 + ci] = (w3[i] >= 0.f) ? 1 : -1;
    }
    if (i < 819200) fw1s[i] = (fw1[i] >= 0.f) ? 1 : -1;
}

// ---------------------------------------------------------------------------
// conv1 (1->64, 3x3, pad1) + bias + maxpool2 + clip + quant -> a1 [b][196][64] u8
// ---------------------------------------------------------------------------
__global__ __launch_bounds__(256, 4) void k_conv1(
    const float* __restrict__ x, const float* __restrict__ w1f,
    const float* __restrict__ b1, unsigned char* __restrict__ a1) {
    __shared__ float sxp[30][33];
    __shared__ float sw[576];
    __shared__ float sb3[64];
    int b = blockIdx.x, tid = threadIdx.x;
    float* sf = &sxp[0][0];
    for (int i = tid; i < 990; i += 256) sf[i] = 0.f;
    for (int i = tid; i < 576; i += 256) sw[i] = (w1f[i] >= 0.f) ? 1.f : -1.f;
    if (tid < 64) sb3[tid] = 3.f * b1[tid];
    __syncthreads();
    for (int i = tid; i < 784; i += 256) {
        int iy = i / 28, ix = i - iy * 28;
        sxp[iy + 1][ix + 1] = x[(size_t)b * 784 + i];
    }
    __syncthreads();

    int cg = tid & 15, pg = tid >> 4;
    float w[4][9], bias3[4];
#pragma unroll
    for (int cc = 0; cc < 4; ++cc) {
#pragma unroll
        for (int k = 0; k < 9; ++k) w[cc][k] = sw[(cg * 4 + cc) * 9 + k];
        bias3[cc] = sb3[cg * 4 + cc];
    }
    if (pg >= 14) return;

    int r0 = pg * 2;
    float xw[4][4];
#pragma unroll
    for (int r = 0; r < 4; ++r)
#pragma unroll
        for (int s = 0; s < 4; ++s) xw[r][s] = sxp[r0 + r][s];

    unsigned char* orow = a1 + (size_t)b * 12544 + (pg * 14) * 64 + cg * 4;
#pragma unroll
    for (int px = 0; px < 14; ++px) {
        unsigned int dw = 0;
#pragma unroll
        for (int cc = 0; cc < 4; ++cc) {
            float mx = 0.f;
#pragma unroll
            for (int dy = 0; dy < 2; ++dy)
#pragma unroll
                for (int dx = 0; dx < 2; ++dx) {
                    float s = w[cc][0] * xw[dy][dx];
#pragma unroll
                    for (int k = 1; k < 9; ++k)
                        s = fmaf(w[cc][k], xw[dy + k / 3][dx + k - (k / 3) * 3], s);
                    mx = (dy == 0 && dx == 0) ? s : fmaxf(mx, s);
                }
            float y3 = fmaf(mx, 3.f, bias3[cc]);
            dw |= quant3(y3) << (8 * cc);
        }
        *(unsigned int*)(orow + px * 64) = dw;
        if (px < 13) {
#pragma unroll
            for (int r = 0; r < 4; ++r) {
                xw[r][0] = xw[r][2];
                xw[r][1] = xw[r][3];
                xw[r][2] = sxp[r0 + r][2 * px + 4];
                xw[r][3] = sxp[r0 + r][2 * px + 5];
            }
        }
    }
}

// ---------------------------------------------------------------------------
// conv2 via i8 MFMA, QUAD-MAPPED M-rows: C-tile row m = pool quad (mt*4+m>>2),
// member (m&3). Each lane's 4 acc ints = one 2x2 pool window -> pooling is
// 3 integer max ops in-register (min+select handles sc<0; affine+quant are
// monotone). No sq LDS buffer, no epilogue barrier, LDS 53760B = 3 blocks/CU.
// ---------------------------------------------------------------------------
__global__ __launch_bounds__(256, 3) void k_conv2_mfma(
    const unsigned char* __restrict__ a1, const char* __restrict__ w2s,
    const float* __restrict__ g1, const float* __restrict__ be1,
    const float* __restrict__ m1, const float* __restrict__ v1,
    unsigned char* __restrict__ a2) {
    __shared__ unsigned char sa[16384];      // [ck][16x16 padded pix][16]
    __shared__ char sw[36864];               // [t][ck][64 co][16]
    __shared__ float ssc[64], sof[64];
    int b = blockIdx.x, tid = threadIdx.x;
    // border zero (60 padded positions x 4 ck)
    if (tid < 240) {
        int ck = tid & 3, e = tid >> 2;
        int py, px;
        if (e < 16)      { py = 0;      px = e; }
        else if (e < 32) { py = 15;     px = e - 16; }
        else if (e < 46) { py = e - 31; px = 0; }
        else             { py = e - 45; px = 15; }
        *(uint4*)(sa + ck * 4096 + (py * 16 + px) * 16) = make_uint4(0, 0, 0, 0);
    }
    {
        const uint4* src = (const uint4*)(a1 + (size_t)b * 12544);
        for (int i = tid; i < 784; i += 256) {
            int pixel = i >> 2, ck = i & 3;
            int py = pixel / 14, px = pixel - py * 14;
            *(uint4*)(sa + ck * 4096 + ((py + 1) * 16 + px + 1) * 16) = src[i];
        }
        for (int u = tid; u < 2304; u += 256) {
            int co = u / 36, rem = u - co * 36;
            int t = rem >> 2, ck = rem & 3;
            *(uint4*)(sw + t * 4096 + ck * 1024 + co * 16) =
                *(const uint4*)(w2s + co * 576 + t * 64 + ck * 16);
        }
        if (tid < 64) {
            float si = g1[tid] * rsqrtf(v1[tid] + 1e-4f);
            ssc[tid] = si;
            sof[tid] = 3.f * (be1[tid] - m1[tid] * si);
        }
    }
    __syncthreads();

    int w = tid >> 6, l = tid & 63;
    int lr = l & 15, lg = l >> 4;
    // A-fragment row = lr: quad s = mt*4 + (lr>>2), member (lr&3)
    int abase[4], mts[4];
#pragma unroll
    for (int j = 0; j < 4; ++j) {
        int mt = w + 4 * j;
        mts[j] = mt;
        int s = mt * 4 + (lr >> 2);
        if (s > 48) s = 48;
        int qy = s / 7, qx = s - qy * 7;
        int ty = 2 * qy + ((lr >> 1) & 1);   // top-left tap in padded coords
        int tx = 2 * qx + (lr & 1);
        abase[j] = lg * 4096 + (ty * 16 + tx) * 16;
    }
    v4i acc[4][4] = {};
#pragma unroll
    for (int t = 0; t < 9; ++t) {
        int ky = t / 3, kx = t - ky * 3;
        int boff = t * 4096 + lg * 1024 + lr * 16;
        v4i bf[4];
#pragma unroll
        for (int nt = 0; nt < 4; ++nt)
            bf[nt] = *(const v4i*)(sw + boff + nt * 256);
        int aoff = (ky * 16 + kx) * 16;
#pragma unroll
        for (int j = 0; j < 4; ++j) {
            if (mts[j] < 13) {
                v4i af = *(const v4i*)(sa + abase[j] + aoff);
#pragma unroll
                for (int nt = 0; nt < 4; ++nt)
                    acc[j][nt] = __builtin_amdgcn_mfma_i32_16x16x64_i8(
                        af, bf[nt], acc[j][nt], 0, 0, 0);
            }
        }
    }

    // epilogue: in-register pool (C row = lg*4+r -> quad mt*4+lg, member r)
#pragma unroll
    for (int j = 0; j < 4; ++j) {
        int q = mts[j] * 4 + lg;
        if (q < 49) {
            unsigned char* outp = a2 + (size_t)b * 3136 + q * 64;
#pragma unroll
            for (int nt = 0; nt < 4; ++nt) {
                int ch = nt * 16 + lr;
                int mx = imax(imax(acc[j][nt][0], acc[j][nt][1]),
                              imax(acc[j][nt][2], acc[j][nt][3]));
                int mn = imin(imin(acc[j][nt][0], acc[j][nt][1]),
                              imin(acc[j][nt][2], acc[j][nt][3]));
                float sc = ssc[ch];
                int v = (sc >= 0.f) ? mx : mn;
                outp[ch] = (unsigned char)quant3(fmaf((float)v, sc, sof[ch]));
            }
        }
    }
}

// ---------------------------------------------------------------------------
// conv3 via i8 MFMA: 4 images per block (folded epilogue)
// ---------------------------------------------------------------------------
__global__ __launch_bounds__(256) void k_conv3_mfma(
    const unsigned char* __restrict__ a2, const char* __restrict__ w3s,
    const float* __restrict__ g2, const float* __restrict__ be2,
    const float* __restrict__ m2, const float* __restrict__ v2,
    unsigned char* __restrict__ a3) {
    __shared__ unsigned char sa[4 * 3136];   // [img][ck][49][16]
    __shared__ char sw[36864];               // [t][ck][64 co][16]
    __shared__ unsigned char so[4 * 2560];   // [img][32 pix][80]
    __shared__ float ssc[64], sof[64];
    int b0 = blockIdx.x * 4, tid = threadIdx.x;
    {
        const uint4* src = (const uint4*)(a2 + (size_t)b0 * 3136);
        for (int i = tid; i < 784; i += 256) {
            int img = i / 196, r = i - img * 196;
            int pixel = r >> 2, ck = r & 3;
            *(uint4*)(sa + img * 3136 + ck * 784 + pixel * 16) = src[i];
        }
        for (int u = tid; u < 2304; u += 256) {
            int co = u / 36, rem = u - co * 36;
            int t = rem >> 2, ck = rem & 3;
            *(uint4*)(sw + t * 4096 + ck * 1024 + co * 16) =
                *(const uint4*)(w3s + co * 576 + t * 64 + ck * 16);
        }
        if (tid < 64) {
            float si = g2[tid] * rsqrtf(v2[tid] + 1e-4f);
            ssc[tid] = si;
            sof[tid] = 3.f * (be2[tid] - m2[tid] * si);
        }
    }
    __syncthreads();

    int w = tid >> 6, l = tid & 63;
    int lr = l & 15, lg = l >> 4;
    const unsigned char* sai = sa + w * 3136;
    int abase[2];
#pragma unroll
    for (int mt = 0; mt < 2; ++mt) {
        int p = mt * 16 + lr;
        if (p > 24) p = 24;
        int oy = p / 5, ox = p - oy * 5;
        abase[mt] = lg * 784 + (oy * 7 + ox) * 16;
    }
    v4i acc[2][4] = {};
#pragma unroll
    for (int t = 0; t < 9; ++t) {
        int ky = t / 3, kx = t - ky * 3;
        int boff = t * 4096 + lg * 1024 + lr * 16;
        v4i bf[4];
#pragma unroll
        for (int nt = 0; nt < 4; ++nt)
            bf[nt] = *(const v4i*)(sw + boff + nt * 256);
        int aoff = (ky * 7 + kx) * 16;
#pragma unroll
        for (int mt = 0; mt < 2; ++mt) {
            v4i af = *(const v4i*)(sai + abase[mt] + aoff);
#pragma unroll
            for (int nt = 0; nt < 4; ++nt)
                acc[mt][nt] = __builtin_amdgcn_mfma_i32_16x16x64_i8(
                    af, bf[nt], acc[mt][nt], 0, 0, 0);
        }
    }

    unsigned char* soi = so + w * 2560;
#pragma unroll
    for (int mt = 0; mt < 2; ++mt)
#pragma unroll
        for (int nt = 0; nt < 4; ++nt) {
            int ch = nt * 16 + lr;
            float sc = ssc[ch], of = sof[ch];
#pragma unroll
            for (int r = 0; r < 4; ++r) {
                int pixel = mt * 16 + lg * 4 + r;
                soi[pixel * 80 + ch] =
                    (unsigned char)quant3(fmaf((float)acc[mt][nt][r], sc, of));
            }
        }
    __syncthreads();
    for (int idx = tid; idx < 400; idx += 256) {
        int img = idx / 100, r = idx - img * 100;
        int p = r >> 2, c0 = r & 3;
        *(uint4*)(a3 + (size_t)(b0 + img) * 1600 + r * 16) =
            *(const uint4*)(so + img * 2560 + p * 80 + c0 * 16);
    }
}

// ---------------------------------------------------------------------------
// fc1 via i8 MFMA: h1[4096][512] = (a3 . fw1s^T)/3 + fb1
// ---------------------------------------------------------------------------
__global__ __launch_bounds__(256) void k_fc1_mfma(
    const unsigned char* __restrict__ a3, const char* __restrict__ fw1s,
    const float* __restrict__ fb1, float* __restrict__ h1) {
    __shared__ unsigned char sA[64 * 80];
    __shared__ unsigned char sB[64 * 80];
    __shared__ float sbias[64];
    int bb = (blockIdx.x >> 3) * 64;
    int ob = (blockIdx.x & 7) * 64;
    int tid = threadIdx.x;
    int row = tid >> 2, seg = tid & 3;
    if (tid < 64) sbias[tid] = fb1[ob + tid];
    const unsigned char* Ag = a3 + (size_t)(bb + row) * 1600 + seg * 16;
    const char* Bg = fw1s + (size_t)(ob + row) * 1600 + seg * 16;
    uint4 av = *(const uint4*)Ag;
    uint4 bv = *(const uint4*)Bg;

    int w = tid >> 6, l = tid & 63;
    int wm = w >> 1, wn = w & 1;
    int lr = l & 15, lg = l >> 4;
    const unsigned char* sAr = sA + (wm * 32 + lr) * 80 + lg * 16;
    const unsigned char* sBr = sB + (wn * 32 + lr) * 80 + lg * 16;
    v4i acc[2][2] = {};

    for (int k0 = 0; k0 < 1600; k0 += 64) {
        *(uint4*)(sA + row * 80 + seg * 16) = av;
        *(uint4*)(sB + row * 80 + seg * 16) = bv;
        __syncthreads();
        if (k0 < 1536) {
            av = *(const uint4*)(Ag + k0 + 64);
            bv = *(const uint4*)(Bg + k0 + 64);
        }
        v4i af0 = *(const v4i*)(sAr);
        v4i af1 = *(const v4i*)(sAr + 16 * 80);
        v4i bf0 = *(const v4i*)(sBr);
        v4i bf1 = *(const v4i*)(sBr + 16 * 80);
        acc[0][0] = __builtin_amdgcn_mfma_i32_16x16x64_i8(af0, bf0, acc[0][0], 0, 0, 0);
        acc[0][1] = __builtin_amdgcn_mfma_i32_16x16x64_i8(af0, bf1, acc[0][1], 0, 0, 0);
        acc[1][0] = __builtin_amdgcn_mfma_i32_16x16x64_i8(af1, bf0, acc[1][0], 0, 0, 0);
        acc[1][1] = __builtin_amdgcn_mfma_i32_16x16x64_i8(af1, bf1, acc[1][1], 0, 0, 0);
        __syncthreads();
    }

    const float inv3 = 1.f / 3.f;
#pragma unroll
    for (int mt = 0; mt < 2; ++mt)
#pragma unroll
        for (int nt = 0; nt < 2; ++nt) {
            int gcol = ob + wn * 32 + nt * 16 + lr;
            float bias = sbias[wn * 32 + nt * 16 + lr];
#pragma unroll
            for (int r = 0; r < 4; ++r) {
                int grow = bb + wm * 32 + mt * 16 + lg * 4 + r;
                h1[(size_t)grow * 512 + gcol] = (float)acc[mt][nt][r] * inv3 + bias;
            }
        }
}

// ---------------------------------------------------------------------------
// fc2 + log_softmax: out[4096][10]
// ---------------------------------------------------------------------------
__global__ __launch_bounds__(256) void k_fc2(
    const float* __restrict__ h1, const float* __restrict__ fw2,
    const float* __restrict__ fb2, float* __restrict__ out) {
    __shared__ float sw[5120];
    __shared__ float sb[16];
    int tid = threadIdx.x;
    for (int i = tid; i < 5120; i += 256) sw[i] = fw2[i];
    if (tid < 10) sb[tid] = fb2[tid];
    __syncthreads();

    int wv = tid >> 6, lane = tid & 63;
    int b = blockIdx.x * 4 + wv;
    const float* hr = h1 + (size_t)b * 512;
    float p[10];
#pragma unroll
    for (int o = 0; o < 10; ++o) p[o] = 0.f;
    for (int k = lane; k < 512; k += 64) {
        float hv = hr[k];
#pragma unroll
        for (int o = 0; o < 10; ++o) p[o] += hv * sw[o * 512 + k];
    }
#pragma unroll
    for (int o = 0; o < 10; ++o) {
#pragma unroll
        for (int off = 32; off > 0; off >>= 1) p[o] += __shfl_xor(p[o], off, 64);
        p[o] += sb[o];
    }
    float mx = p[0];
#pragma unroll
    for (int o = 1; o < 10; ++o) mx = fmaxf(mx, p[o]);
    float se = 0.f;
#pragma unroll
    for (int o = 0; o < 10; ++o) se += expf(p[o] - mx);
    float lse = logf(se) + mx;
    float myv = 0.f;
#pragma unroll
    for (int o = 0; o < 10; ++o) myv = (lane == o) ? p[o] : myv;
    if (lane < 10) out[(size_t)b * 10 + lane] = myv - lse;
}

// ---------------------------------------------------------------------------
extern "C" void kernel_launch(void* const* d_in, const int* in_sizes, int n_in,
                              void* d_out, int out_size, void* d_ws, size_t ws_size,
                              hipStream_t stream) {
    const float* x   = (const float*)d_in[0];
    const float* w1  = (const float*)d_in[1];
    const float* b1  = (const float*)d_in[2];
    const float* w2  = (const float*)d_in[3];
    const float* g1  = (const float*)d_in[4];
    const float* be1 = (const float*)d_in[5];
    const float* m1  = (const float*)d_in[6];
    const float* v1  = (const float*)d_in[7];
    const float* w3  = (const float*)d_in[8];
    const float* g2  = (const float*)d_in[9];
    const float* be2 = (const float*)d_in[10];
    const float* m2  = (const float*)d_in[11];
    const float* v2  = (const float*)d_in[12];
    const float* fw1 = (const float*)d_in[13];
    const float* fb1 = (const float*)d_in[14];
    const float* fw2 = (const float*)d_in[15];
    const float* fb2 = (const float*)d_in[16];
    float* out = (float*)d_out;

    char* ws = (char*)d_ws;
    char* w2s  = ws;                                   // 36864
    char* w3s  = ws + 36864;                           // 36864
    char* fw1s = ws + 73728;                           // 819200
    unsigned char* a1 = (unsigned char*)(ws + 892928); // 4096*12544 = 51380224
    unsigned char* a2 = a1 + 51380224;                 // 4096*3136  = 12845056
    unsigned char* a3 = a2 + 12845056;                 // 4096*1600  = 6553600
    float* h1 = (float*)(void*)a1;                     // alias: a1 dead when fc1 runs

    k_signs<<<3200, 256, 0, stream>>>(w2, w3, fw1, w2s, w3s, fw1s);
    k_conv1<<<4096, 256, 0, stream>>>(x, w1, b1, a1);
    k_conv2_mfma<<<4096, 256, 0, stream>>>(a1, w2s, g1, be1, m1, v1, a2);
    k_conv3_mfma<<<1024, 256, 0, stream>>>(a2, w3s, g2, be2, m2, v2, a3);
    k_fc1_mfma<<<512, 256, 0, stream>>>(a3, fw1s, fb1, h1);
    k_fc2<<<1024, 256, 0, stream>>>(h1, fw2, fb2, out);
}